// Round 2
// baseline (263.214 us; speedup 1.0000x reference)
//
#include <hip/hip_runtime.h>
#include <hip/hip_bf16.h>
#include <hip/hip_fp16.h>

#define N_NODES 100000
#define E_EDGES 400000
#define B_SUB 2048
#define INIT_DIM 100
#define UFD 100
#define ENT_DIM 400
#define GCN 128
#define NR2 100
#define KPAD 416           // 400 rounded up to 13*32
#define NCH 13             // K chunks of 32
#define CAP 64             // bucket capacity per dst (P(cnt>=64) < 1e-60 at lambda=4)

typedef __attribute__((ext_vector_type(8))) short shortx8;
typedef __attribute__((ext_vector_type(4))) float floatx4;

// output element offsets (fp32 outputs, concatenated: sub_emb, r, x)
#define OUT_R_OFF ((long)B_SUB * GCN)
#define OUT_X_OFF ((long)(B_SUB + NR2) * GCN)

__device__ __forceinline__ unsigned short f2b(float f) {
    unsigned u = __float_as_uint(f);
    u += 0x7fffu + ((u >> 16) & 1u);   // RNE to bf16
    return (unsigned short)(u >> 16);
}
// pack two fp32 -> bf16x2 (x in low 16, y in high 16)
__device__ __forceinline__ unsigned pk2(float x, float y) {
    return (unsigned)f2b(x) | ((unsigned)f2b(y) << 16);
}
// single-instruction packed convert (identical RNE result to pk2)
__device__ __forceinline__ unsigned cvtpk2(float x, float y) {
    unsigned r;
    asm("v_cvt_pk_bf16_f32 %0, %1, %2" : "=v"(r) : "v"(x), "v"(y));
    return r;
}
__device__ __forceinline__ float blo(unsigned u) { return __uint_as_float(u << 16); }
__device__ __forceinline__ float bhi(unsigned u) { return __uint_as_float(u & 0xFFFF0000u); }

// ---------------- W transpose + fp32->bf16 (also zeroes bucket cursors) ----------------
__global__ void wt_kernel(const float* __restrict__ W, unsigned short* __restrict__ Wt,
                          int* __restrict__ cursor) {
    int idx = blockIdx.x * 256 + threadIdx.x;   // grid covers max(53248, 100000)
    if (idx < GCN * KPAD) {
        int n = idx & 127, k = idx >> 7;
        unsigned short o = 0;
        if (k < ENT_DIM) o = f2b(W[(long)k * GCN + n]);
        Wt[(long)n * KPAD + k] = o;
    }
    if (idx < N_NODES) cursor[idx] = 0;
}

// ---------------- relation GEMMs (tiny, fp32 exact) ----------------
__global__ void rel_kernel(const float* __restrict__ init_rel, const float* __restrict__ Wr,
                           const float* __restrict__ Wrel, const float* __restrict__ att_src,
                           unsigned* __restrict__ rp_b, float* __restrict__ rproj_att,
                           float* __restrict__ out_r) {
    int rel = blockIdx.x;
    int tx = threadIdx.x;  // 0..127
    __shared__ float rl[ENT_DIM];
    __shared__ float accbuf[128];
    for (int k = tx; k < ENT_DIM; k += 128) rl[k] = init_rel[(long)rel * ENT_DIM + k];
    __syncthreads();
    float acc1 = 0.f, acc2 = 0.f;
    for (int k = 0; k < ENT_DIM; ++k) {
        float v = rl[k];
        acc1 += v * Wr[(long)k * GCN + tx];
        acc2 += v * Wrel[(long)k * GCN + tx];
    }
    out_r[rel * GCN + tx] = acc2;
    accbuf[tx] = acc1;
    int head = tx >> 6, d = tx & 63;
    float v = acc1 * att_src[head * 64 + d];
    for (int off = 32; off > 0; off >>= 1) v += __shfl_down(v, off, 64);
    if (d == 0) rproj_att[rel * 2 + head] = v;
    __syncthreads();
    if (tx < 64) rp_b[rel * 64 + tx] = pk2(accbuf[tx], accbuf[tx + 64]);
}

// ---------------- node GEMM h = init_embed @ W via bf16 MFMA ----------------
// v3: B fragments loaded DIRECTLY from global (Wt is 106 KB, L2-resident on
// every XCD) -> zero main-loop LDS, zero main-loop barriers, zero bank
// conflicts. Each wave computes 64 rows x 64 cols (4x4 fragments). Register
// double-buffer (static even/odd) pipelines chunk k+1 loads under chunk k
// MFMAs via loop-carried deps. Column split {hc*32..+31, hc*32+64..+95}
// keeps the h_b pk2(j, j+64) pairing wave-local; att partials exchanged
// through 4 KB LDS with a single epilogue barrier.
__device__ __forceinline__ float4 load_seg2(const float* __restrict__ id_embed,
                                            const float* __restrict__ gtab,
                                            const float* __restrict__ atab,
                                            const float* __restrict__ ltab,
                                            int ido, int go, int ao, int lo, int kg) {
    const float* p;
    if (kg < 100)      p = id_embed + ido + kg;
    else if (kg < 200) p = gtab + go + (kg - 100);
    else if (kg < 300) p = atab + ao + (kg - 200);
    else if (kg < 400) p = ltab + lo + (kg - 300);
    else               p = id_embed + ido;          // k>=400 hits zero rows of Wt
    return *(const float4*)p;
}

__global__ __launch_bounds__(256, 2) void hgemm_kernel(
        const float* __restrict__ id_embed, const float* __restrict__ gtab,
        const float* __restrict__ atab, const float* __restrict__ ltab,
        const int* __restrict__ ent_feature, const unsigned short* __restrict__ Wt,
        const float* __restrict__ att_src, const float* __restrict__ att_dst,
        unsigned* __restrict__ h_b, float* __restrict__ hsrc_att, float* __restrict__ hdst_att) {
    __shared__ float4 attp[2][128];                 // att partial exchange (4 KB)
    int t = threadIdx.x;
    int w = t >> 6, lane = t & 63, quad = lane >> 4, l16 = lane & 15;
    int rowhalf = w >> 1, hc = w & 1;
    int n0 = blockIdx.x * 128;
    int rb = n0 + rowhalf * 64;

    // per-row-tile A offsets (int offsets, shared SGPR bases)
    int ido[4], go[4], ao[4], lo[4];
#pragma unroll
    for (int rt = 0; rt < 4; ++rt) {
        int nrow = rb + rt * 16 + l16;
        int nc = nrow < N_NODES ? nrow : N_NODES - 1;
        ido[rt] = nc * INIT_DIM;
        go[rt] = ent_feature[nc * 3] * UFD;
        ao[rt] = ent_feature[nc * 3 + 1] * UFD;
        lo[rt] = ent_feature[nc * 3 + 2] * UFD;
    }
    // per-col-tile B pointers: cols {hc*32+0..15, +16..31, +64..79, +80..95}
    const unsigned short* bp[4];
#pragma unroll
    for (int ct = 0; ct < 4; ++ct) {
        int col = hc * 32 + (ct & 1) * 16 + (ct >> 1) * 64 + l16;
        bp[ct] = Wt + (long)col * KPAD + quad * 8;
    }

    floatx4 acc[4][4];
#pragma unroll
    for (int rt = 0; rt < 4; ++rt)
#pragma unroll
        for (int ct = 0; ct < 4; ++ct) acc[rt][ct] = (floatx4){0.f, 0.f, 0.f, 0.f};

    float4 a0[8], a1[8];
    shortx8 b0[4], b1[4];

#define LOADB(buf, ch_) {                                                   \
    _Pragma("unroll") for (int ct = 0; ct < 4; ++ct)                        \
        buf[ct] = *(const shortx8*)&bp[ct][(ch_) * 32]; }
#define LOADA(buf, ch_) {                                                   \
    int kg_ = (ch_) * 32 + quad * 8;                                        \
    _Pragma("unroll") for (int rt = 0; rt < 4; ++rt) {                      \
        buf[rt * 2]     = load_seg2(id_embed, gtab, atab, ltab,             \
                                    ido[rt], go[rt], ao[rt], lo[rt], kg_);  \
        buf[rt * 2 + 1] = load_seg2(id_embed, gtab, atab, ltab,             \
                                    ido[rt], go[rt], ao[rt], lo[rt], kg_ + 4); \
    } }
#define COMP(abuf, bbuf) {                                                  \
    _Pragma("unroll") for (int rt = 0; rt < 4; ++rt) {                      \
        uint4 u_;                                                           \
        u_.x = cvtpk2(abuf[rt * 2].x,     abuf[rt * 2].y);                  \
        u_.y = cvtpk2(abuf[rt * 2].z,     abuf[rt * 2].w);                  \
        u_.z = cvtpk2(abuf[rt * 2 + 1].x, abuf[rt * 2 + 1].y);              \
        u_.w = cvtpk2(abuf[rt * 2 + 1].z, abuf[rt * 2 + 1].w);              \
        shortx8 af_ = *(shortx8*)&u_;                                       \
        _Pragma("unroll") for (int ct = 0; ct < 4; ++ct)                    \
            acc[rt][ct] = __builtin_amdgcn_mfma_f32_16x16x32_bf16(          \
                af_, bbuf[ct], acc[rt][ct], 0, 0, 0);                       \
    } }

    LOADB(b0, 0);
    LOADA(a0, 0);
#pragma unroll
    for (int ch = 0; ch < 12; ch += 2) {
        LOADB(b1, ch + 1);
        LOADA(a1, ch + 1);
        COMP(a0, b0);                   // chunk ch
        LOADB(b0, ch + 2);
        LOADA(a0, ch + 2);
        COMP(a1, b1);                   // chunk ch+1
    }
    COMP(a0, b0);                       // chunk 12

    // epilogue ------------------------------------------------------------
    float attS_r[4], attD_r[4];
#pragma unroll
    for (int ct = 0; ct < 4; ++ct) {
        int col = hc * 32 + (ct & 1) * 16 + (ct >> 1) * 64 + l16;
        attS_r[ct] = att_src[col];
        attD_r[ct] = att_dst[col];
    }
#pragma unroll
    for (int rt = 0; rt < 4; ++rt) {
        int baseRow = rb + rt * 16 + quad * 4;
#pragma unroll
        for (int i = 0; i < 4; ++i) {
            int node = baseRow + i;
            bool ok = node < N_NODES;
#pragma unroll
            for (int p = 0; p < 2; ++p)
                if (ok) h_b[(long)node * 64 + hc * 32 + p * 16 + l16] =
                            pk2(acc[rt][p][i], acc[rt][p + 2][i]);
            float s0 = acc[rt][0][i] * attS_r[0] + acc[rt][1][i] * attS_r[1];
            float s1 = acc[rt][2][i] * attS_r[2] + acc[rt][3][i] * attS_r[3];
            float d0 = acc[rt][0][i] * attD_r[0] + acc[rt][1][i] * attD_r[1];
            float d1 = acc[rt][2][i] * attD_r[2] + acc[rt][3][i] * attD_r[3];
#pragma unroll
            for (int m = 1; m < 16; m <<= 1) {
                s0 += __shfl_xor(s0, m, 64);
                s1 += __shfl_xor(s1, m, 64);
                d0 += __shfl_xor(d0, m, 64);
                d1 += __shfl_xor(d1, m, 64);
            }
            if (l16 == 0)
                attp[hc][rowhalf * 64 + rt * 16 + quad * 4 + i] = make_float4(s0, s1, d0, d1);
        }
    }
    __syncthreads();
    if (hc == 0) {                      // waves 0,2 combine + write att sums
        int r = rowhalf * 64 + lane;
        int node = n0 + r;
        if (node < N_NODES) {
            float4 pa_ = attp[0][r], pb_ = attp[1][r];
            *(float2*)&hsrc_att[node * 2] = make_float2(pa_.x + pb_.x, pa_.y + pb_.y);
            *(float2*)&hdst_att[node * 2] = make_float2(pa_.z + pb_.z, pa_.w + pb_.w);
        }
    }
#undef LOADA
#undef LOADB
#undef COMP
}

// ---------------- edge fill: bucket scatter, one 8B store per edge ----------------
// ebuf[dst*CAP + pos] = { (et<<17)|src, half2(exp(logit0), exp(logit1)) }
__global__ void fill_kernel(const int* __restrict__ edge_index, const int* __restrict__ edge_type,
                            int* __restrict__ cursor,
                            const float2* __restrict__ hsrc2, const float2* __restrict__ rpa2,
                            const float2* __restrict__ hdst2,
                            uint2* __restrict__ ebuf) {
    int e = blockIdx.x * blockDim.x + threadIdx.x;
    if (e >= E_EDGES) return;
    int src = edge_index[e];
    int dst = edge_index[E_EDGES + e];
    int et = edge_type[e];
    float2 hs = hsrc2[src];
    float2 ra = rpa2[et];
    float2 hd = hdst2[dst];
    float x0 = hs.x + ra.x + hd.x;
    float x1 = hs.y + ra.y + hd.y;
    x0 = x0 > 0.f ? x0 : 0.2f * x0;      // leaky_relu(0.2)
    x1 = x1 > 0.f ? x1 : 0.2f * x1;
    __half2 hh = __floats2half2_rn(__expf(x0), __expf(x1));
    union { __half2 h; unsigned u; } cv; cv.h = hh;
    int pos = atomicAdd(&cursor[dst], 1);
    if (pos < CAP)
        ebuf[(long)dst * CAP + pos] = make_uint2(((unsigned)et << 17) | (unsigned)src, cv.u);
}

// ---------------- per-dst aggregation: wave per dst ----------------
__global__ __launch_bounds__(256) void agg_kernel(
        const int* __restrict__ cursor, const uint2* __restrict__ ebuf,
        const unsigned* __restrict__ h_b, const unsigned* __restrict__ rp_b,
        float* __restrict__ out_x) {
    int w = threadIdx.x >> 6, l = threadIdx.x & 63;
    int dst = blockIdx.x * 4 + w;           // grid = 25000, exact
    int cnt = cursor[dst];
    if (cnt > CAP) cnt = CAP;
    const uint2* base = ebuf + (long)dst * CAP;
    float acc0 = 0.f, acc1 = 0.f, den0 = 0.f, den1 = 0.f;
    int j = 0;
    for (; j + 3 < cnt; j += 4) {
        uint2 v0 = base[j], v1 = base[j + 1], v2 = base[j + 2], v3 = base[j + 3];
        union { __half2 h; unsigned u; } c0, c1, c2, c3;
        c0.u = v0.y; c1.u = v1.y; c2.u = v2.y; c3.u = v3.y;
        float2 e0 = __half22float2(c0.h), e1 = __half22float2(c1.h);
        float2 e2 = __half22float2(c2.h), e3 = __half22float2(c3.h);
        unsigned hb0 = h_b[(long)(v0.x & 0x1FFFF) * 64 + l];
        unsigned hb1 = h_b[(long)(v1.x & 0x1FFFF) * 64 + l];
        unsigned hb2 = h_b[(long)(v2.x & 0x1FFFF) * 64 + l];
        unsigned hb3 = h_b[(long)(v3.x & 0x1FFFF) * 64 + l];
        unsigned rb0 = rp_b[(v0.x >> 17) * 64 + l];
        unsigned rb1 = rp_b[(v1.x >> 17) * 64 + l];
        unsigned rb2 = rp_b[(v2.x >> 17) * 64 + l];
        unsigned rb3 = rp_b[(v3.x >> 17) * 64 + l];
        acc0 += e0.x * (blo(hb0) + blo(rb0)) + e1.x * (blo(hb1) + blo(rb1))
              + e2.x * (blo(hb2) + blo(rb2)) + e3.x * (blo(hb3) + blo(rb3));
        acc1 += e0.y * (bhi(hb0) + bhi(rb0)) + e1.y * (bhi(hb1) + bhi(rb1))
              + e2.y * (bhi(hb2) + bhi(rb2)) + e3.y * (bhi(hb3) + bhi(rb3));
        den0 += e0.x + e1.x + e2.x + e3.x;
        den1 += e0.y + e1.y + e2.y + e3.y;
    }
    for (; j < cnt; ++j) {
        uint2 v0 = base[j];
        union { __half2 h; unsigned u; } c0; c0.u = v0.y;
        float2 e0 = __half22float2(c0.h);
        unsigned hb = h_b[(long)(v0.x & 0x1FFFF) * 64 + l];
        unsigned rb = rp_b[(v0.x >> 17) * 64 + l];
        acc0 += e0.x * (blo(hb) + blo(rb));
        acc1 += e0.y * (bhi(hb) + bhi(rb));
        den0 += e0.x;
        den1 += e0.y;
    }
    float i0 = 1.0f / (den0 + 1e-16f), i1 = 1.0f / (den1 + 1e-16f);
    // nontemporal: out_x is 51.2MB streaming; keep h_b hot in L2 instead
    __builtin_nontemporal_store(tanhf(acc0 * i0), &out_x[(long)dst * GCN + l]);
    __builtin_nontemporal_store(tanhf(acc1 * i1), &out_x[(long)dst * GCN + 64 + l]);
}

// ---------------- sub gather ----------------
__global__ void gather_kernel(const int* __restrict__ sub, const float* __restrict__ out_x,
                              float* __restrict__ out_sub) {
    int idx = blockIdx.x * blockDim.x + threadIdx.x;
    if (idx >= B_SUB * GCN) return;
    int b = idx >> 7, d = idx & 127;
    out_sub[idx] = out_x[(long)sub[b] * GCN + d];
}

extern "C" void kernel_launch(void* const* d_in, const int* in_sizes, int n_in,
                              void* d_out, int out_size, void* d_ws, size_t ws_size,
                              hipStream_t stream) {
    const int* edge_index = (const int*)d_in[0];
    const int* edge_type  = (const int*)d_in[1];
    const int* ent_feature = (const int*)d_in[3];
    const int* sub = (const int*)d_in[4];
    const float* id_embed = (const float*)d_in[7];
    const float* gtab = (const float*)d_in[8];
    const float* atab = (const float*)d_in[9];
    const float* ltab = (const float*)d_in[10];
    const float* init_rel = (const float*)d_in[11];
    const float* W = (const float*)d_in[12];
    const float* Wr = (const float*)d_in[13];
    const float* att_src = (const float*)d_in[14];
    const float* att_dst = (const float*)d_in[15];
    const float* Wrel = (const float*)d_in[16];

    char* ws = (char*)d_ws;
    unsigned* h_b = (unsigned*)ws;                          ws += (long)N_NODES * 64 * 4;    // 25.6 MB
    unsigned* rp_b = (unsigned*)ws;                         ws += (long)NR2 * 64 * 4;
    float* rproj_att = (float*)ws;                          ws += NR2 * 2 * 4;
    float* hsrc_att = (float*)ws;                           ws += (long)N_NODES * 2 * 4;
    float* hdst_att = (float*)ws;                           ws += (long)N_NODES * 2 * 4;
    unsigned short* Wt = (unsigned short*)ws;               ws += (long)GCN * KPAD * 2;
    int* cursor = (int*)ws;                                 ws += (long)N_NODES * 4;
    uint2* ebuf = (uint2*)ws;                               ws += (long)N_NODES * CAP * 8;   // 51.2 MB

    float* out = (float*)d_out;
    float* out_sub = out;
    float* out_r = out + OUT_R_OFF;
    float* out_x = out + OUT_X_OFF;

    const int NB = (N_NODES + 255) / 256;   // 391

    wt_kernel<<<NB, 256, 0, stream>>>(W, Wt, cursor);       // also zeroes cursor
    rel_kernel<<<NR2, 128, 0, stream>>>(init_rel, Wr, Wrel, att_src, rp_b, rproj_att, out_r);
    hgemm_kernel<<<(N_NODES + 127) / 128, 256, 0, stream>>>(id_embed, gtab, atab, ltab,
                                                            ent_feature, Wt, att_src, att_dst,
                                                            h_b, hsrc_att, hdst_att);
    fill_kernel<<<(E_EDGES + 255) / 256, 256, 0, stream>>>(edge_index, edge_type, cursor,
                                                           (const float2*)hsrc_att,
                                                           (const float2*)rproj_att,
                                                           (const float2*)hdst_att, ebuf);
    agg_kernel<<<N_NODES / 4, 256, 0, stream>>>(cursor, ebuf, h_b, rp_b, out_x);
    gather_kernel<<<(B_SUB * GCN + 255) / 256, 256, 0, stream>>>(sub, out_x, out_sub);
}

// Round 4
// 233.668 us; speedup vs baseline: 1.1264x; 1.1264x over previous
//
#include <hip/hip_runtime.h>
#include <hip/hip_bf16.h>
#include <hip/hip_fp16.h>

#define N_NODES 100000
#define E_EDGES 400000
#define B_SUB 2048
#define INIT_DIM 100
#define UFD 100
#define ENT_DIM 400
#define GCN 128
#define NR2 100
#define KPAD 416           // 400 rounded up to 13*32
#define NCH 13             // K chunks of 32
#define CHK 32             // k per chunk
#define CAP 64             // bucket capacity per dst

typedef __attribute__((ext_vector_type(8))) short shortx8;
typedef __attribute__((ext_vector_type(4))) float floatx4;

#define OUT_R_OFF ((long)B_SUB * GCN)
#define OUT_X_OFF ((long)(B_SUB + NR2) * GCN)

__device__ __forceinline__ unsigned short f2b(float f) {
    unsigned u = __float_as_uint(f);
    u += 0x7fffu + ((u >> 16) & 1u);   // RNE to bf16
    return (unsigned short)(u >> 16);
}
__device__ __forceinline__ unsigned pk2(float x, float y) {
    return (unsigned)f2b(x) | ((unsigned)f2b(y) << 16);
}
// single-instruction packed RNE convert (bit-identical to pk2; harness-verified
// R0->R2: absmax byte-identical)
__device__ __forceinline__ unsigned cvtpk2(float x, float y) {
    unsigned r;
    asm("v_cvt_pk_bf16_f32 %0, %1, %2" : "=v"(r) : "v"(x), "v"(y));
    return r;
}
__device__ __forceinline__ float blo(unsigned u) { return __uint_as_float(u << 16); }
__device__ __forceinline__ float bhi(unsigned u) { return __uint_as_float(u & 0xFFFF0000u); }

// ---------------- W transpose + fp32->bf16 (also zeroes bucket cursors) ----------------
__global__ void wt_kernel(const float* __restrict__ W, unsigned short* __restrict__ Wt,
                          int* __restrict__ cursor) {
    int idx = blockIdx.x * 256 + threadIdx.x;
    if (idx < GCN * KPAD) {
        int n = idx & 127, k = idx >> 7;
        unsigned short o = 0;
        if (k < ENT_DIM) o = f2b(W[(long)k * GCN + n]);
        Wt[(long)n * KPAD + k] = o;
    }
    if (idx < N_NODES) cursor[idx] = 0;
}

// ---------------- relation GEMMs (tiny, fp32) ----------------
// k split 2-way across 256 threads (chain halved) + unroll 8 for ILP.
__global__ __launch_bounds__(256) void rel_kernel(
        const float* __restrict__ init_rel, const float* __restrict__ Wr,
        const float* __restrict__ Wrel, const float* __restrict__ att_src,
        unsigned* __restrict__ rp_b, float* __restrict__ rproj_att,
        float* __restrict__ out_r) {
    int rel = blockIdx.x;
    int t = threadIdx.x;            // 0..255
    int tx = t & 127, kh = t >> 7;  // output col, k-half
    __shared__ float rl[ENT_DIM];
    __shared__ float p1[2][128], p2[2][128];
    __shared__ float accbuf[128];
    for (int k = t; k < ENT_DIM; k += 256) rl[k] = init_rel[(long)rel * ENT_DIM + k];
    __syncthreads();
    float a1 = 0.f, a2 = 0.f;
    {
        const float* wr = Wr + (long)(kh * 200) * GCN + tx;
        const float* wl = Wrel + (long)(kh * 200) * GCN + tx;
        const float* rv = rl + kh * 200;
#pragma unroll 8
        for (int k = 0; k < 200; ++k) {
            float v = rv[k];
            a1 += v * wr[(long)k * GCN];
            a2 += v * wl[(long)k * GCN];
        }
    }
    p1[kh][tx] = a1;
    p2[kh][tx] = a2;
    __syncthreads();
    if (t < 128) {
        float acc1 = p1[0][tx] + p1[1][tx];
        float acc2 = p2[0][tx] + p2[1][tx];
        out_r[rel * GCN + tx] = acc2;
        accbuf[tx] = acc1;
        int head = tx >> 6, d = tx & 63;
        float v = acc1 * att_src[head * 64 + d];
        for (int off = 32; off > 0; off >>= 1) v += __shfl_down(v, off, 64);
        if (d == 0) rproj_att[rel * 2 + head] = v;
    }
    __syncthreads();
    if (t < 64) rp_b[rel * 64 + t] = pk2(accbuf[t], accbuf[t + 64]);
}

// ---------------- node GEMM h = init_embed @ W via bf16 MFMA ----------------
// v5: R3's DMA staging + XOR swizzle, but with the SAFE 2-phase sync
// (T3-minimum recipe): double buffer, ONE __syncthreads per chunk (full
// fence: vmcnt(0)+barrier, compiler cannot reorder/miscount), STAGE(ch+1)
// issued right after the barrier so the DMA flies under COMPUTE(ch).
// Swizzle (bank-floor, rule-21 both-sides):
//   A slots:  phys = logical ^ (row & 7)      (8x 16B slots per 128 B row)
//   B slots:  phys = logical ^ ((col>>1) & 3) (4x 16B slots per 64 B col)
__global__ __launch_bounds__(256) void hgemm_kernel(
        const float* __restrict__ id_embed, const float* __restrict__ gtab,
        const float* __restrict__ atab, const float* __restrict__ ltab,
        const int* __restrict__ ent_feature, const unsigned short* __restrict__ Wt,
        const float* __restrict__ att_src, const float* __restrict__ att_dst,
        unsigned* __restrict__ h_b, float* __restrict__ hsrc_att, float* __restrict__ hdst_att) {
    __shared__ __align__(16) float As[2][64 * CHK];            // 8 KB per buf
    __shared__ __align__(16) unsigned short Bs[2][128 * CHK];  // 8 KB per buf

    int t = threadIdx.x;
    int w = t >> 6, lane = t & 63, quad = lane >> 4, l16 = lane & 15;
    int n0 = blockIdx.x * 64;

    // ---- staging source setup ----
    // A: thread t feeds rows {t>>3, 32+(t>>3)}, phys slot = t&7 (16B units);
    //    supplies logical slot (t&7) ^ (row&7)  (rows differ by 32 -> same &7).
    int rA = t >> 3;
    int lA4 = ((t & 7) ^ (rA & 7)) * 4;        // logical k offset within chunk (floats)
    const float* segp[2][4];
#pragma unroll
    for (int rr = 0; rr < 2; ++rr) {
        int node = n0 + rr * 32 + rA;
        int nc = node < N_NODES ? node : N_NODES - 1;
        segp[rr][0] = id_embed + (long)nc * INIT_DIM;
        segp[rr][1] = gtab + ent_feature[nc * 3] * UFD;
        segp[rr][2] = atab + ent_feature[nc * 3 + 1] * UFD;
        segp[rr][3] = ltab + ent_feature[nc * 3 + 2] * UFD;
    }
    // B: thread t feeds cols {t>>2, 64+(t>>2)}, phys slot = t&3;
    //    supplies logical slot (t&3) ^ ((col>>1)&3) = (t&3) ^ ((t>>3)&3).
    int cB = t >> 2;
    int lB8 = ((t & 3) ^ ((t >> 3) & 3)) * 8;  // shorts offset within chunk
    const unsigned short* bsrc0 = Wt + (long)cB * KPAD + lB8;
    const unsigned short* bsrc1 = Wt + (long)(64 + cB) * KPAD + lB8;

#define SEGPTR(rr_, kg_) ((kg_) < 100 ? segp[rr_][0] + (kg_) : \
                          (kg_) < 200 ? segp[rr_][1] + ((kg_) - 100) : \
                          (kg_) < 300 ? segp[rr_][2] + ((kg_) - 200) : \
                          (kg_) < 400 ? segp[rr_][3] + ((kg_) - 300) : segp[rr_][0])

    // 4 DMA issues per thread per chunk; LDS dest = wave-uniform base (+HW lane*16)
#define STAGE(ch_, bi_) { \
    int kgA_ = (ch_) * CHK + lA4; \
    __builtin_amdgcn_global_load_lds( \
        (const __attribute__((address_space(1))) unsigned*)SEGPTR(0, kgA_), \
        (__attribute__((address_space(3))) unsigned*)((char*)&As[bi_][0] + w * 1024), 16, 0, 0); \
    __builtin_amdgcn_global_load_lds( \
        (const __attribute__((address_space(1))) unsigned*)SEGPTR(1, kgA_), \
        (__attribute__((address_space(3))) unsigned*)((char*)&As[bi_][0] + 4096 + w * 1024), 16, 0, 0); \
    __builtin_amdgcn_global_load_lds( \
        (const __attribute__((address_space(1))) unsigned*)(bsrc0 + (ch_) * CHK), \
        (__attribute__((address_space(3))) unsigned*)((char*)&Bs[bi_][0] + w * 1024), 16, 0, 0); \
    __builtin_amdgcn_global_load_lds( \
        (const __attribute__((address_space(1))) unsigned*)(bsrc1 + (ch_) * CHK), \
        (__attribute__((address_space(3))) unsigned*)((char*)&Bs[bi_][0] + 4096 + w * 1024), 16, 0, 0); \
}

    floatx4 acc[8];
#pragma unroll
    for (int c = 0; c < 8; ++c) acc[c] = (floatx4){0.f, 0.f, 0.f, 0.f};

    // read-side swizzle constants
    int xA0 = (2 * quad) ^ (l16 & 7);          // phys slot of logical granule 2q
    int xA1 = (2 * quad + 1) ^ (l16 & 7);      // phys slot of logical granule 2q+1
    int qB = quad ^ ((l16 >> 1) & 3);          // phys B slot

#define COMPUTE(bi_) { \
    const float* arow_ = &As[bi_][0] + (w * 16 + l16) * CHK; \
    float4 fa0_ = *(const float4*)(arow_ + xA0 * 4); \
    float4 fa1_ = *(const float4*)(arow_ + xA1 * 4); \
    uint4 u_; \
    u_.x = cvtpk2(fa0_.x, fa0_.y); u_.y = cvtpk2(fa0_.z, fa0_.w); \
    u_.z = cvtpk2(fa1_.x, fa1_.y); u_.w = cvtpk2(fa1_.z, fa1_.w); \
    shortx8 af_ = *(shortx8*)&u_; \
    _Pragma("unroll") for (int c = 0; c < 8; ++c) { \
        shortx8 b_ = *(const shortx8*)(&Bs[bi_][0] + (c * 16 + l16) * CHK + qB * 8); \
        acc[c] = __builtin_amdgcn_mfma_f32_16x16x32_bf16(af_, b_, acc[c], 0, 0, 0); \
    } \
}

    STAGE(0, 0);
#pragma unroll
    for (int ch = 0; ch < NCH; ++ch) {
        __syncthreads();                  // vmcnt(0)+barrier: buf[ch&1] landed everywhere,
                                          // and everyone is done reading buf[(ch&1)^1]
        if (ch + 1 < NCH) STAGE(ch + 1, (ch & 1) ^ 1);   // fire-and-forget; flies under COMPUTE
        COMPUTE(ch & 1);
    }
#undef STAGE
#undef COMPUTE
#undef SEGPTR

    // epilogue: C/D layout col=lane&15 (-> c*16+l16), row=quad*4+reg (R0-verified)
    float attS_r[8], attD_r[8];
#pragma unroll
    for (int c = 0; c < 8; ++c) {
        attS_r[c] = att_src[c * 16 + l16];
        attD_r[c] = att_dst[c * 16 + l16];
    }
    int baseRow = n0 + w * 16 + quad * 4;
#pragma unroll
    for (int i = 0; i < 4; ++i) {
        int node = baseRow + i;
        bool ok = node < N_NODES;
#pragma unroll
        for (int c = 0; c < 4; ++c)
            if (ok) h_b[(long)node * 64 + c * 16 + l16] = cvtpk2(acc[c][i], acc[c + 4][i]);
        float s0 = 0.f, s1 = 0.f, d0 = 0.f, d1 = 0.f;
#pragma unroll
        for (int c = 0; c < 8; ++c) {
            float v = acc[c][i];
            if (c < 4) { s0 += v * attS_r[c]; d0 += v * attD_r[c]; }
            else       { s1 += v * attS_r[c]; d1 += v * attD_r[c]; }
        }
#pragma unroll
        for (int m = 1; m < 16; m <<= 1) {
            s0 += __shfl_xor(s0, m, 64);
            s1 += __shfl_xor(s1, m, 64);
            d0 += __shfl_xor(d0, m, 64);
            d1 += __shfl_xor(d1, m, 64);
        }
        if (ok && l16 == 0) {
            *(float2*)&hsrc_att[node * 2] = make_float2(s0, s1);
            *(float2*)&hdst_att[node * 2] = make_float2(d0, d1);
        }
    }
}

// ---------------- edge fill: bucket scatter, one 8B store per edge ----------------
__global__ void fill_kernel(const int* __restrict__ edge_index, const int* __restrict__ edge_type,
                            int* __restrict__ cursor,
                            const float2* __restrict__ hsrc2, const float2* __restrict__ rpa2,
                            const float2* __restrict__ hdst2,
                            uint2* __restrict__ ebuf) {
    int e = blockIdx.x * blockDim.x + threadIdx.x;
    if (e >= E_EDGES) return;
    int src = edge_index[e];
    int dst = edge_index[E_EDGES + e];
    int et = edge_type[e];
    float2 hs = hsrc2[src];
    float2 ra = rpa2[et];
    float2 hd = hdst2[dst];
    float x0 = hs.x + ra.x + hd.x;
    float x1 = hs.y + ra.y + hd.y;
    x0 = x0 > 0.f ? x0 : 0.2f * x0;      // leaky_relu(0.2)
    x1 = x1 > 0.f ? x1 : 0.2f * x1;
    __half2 hh = __floats2half2_rn(__expf(x0), __expf(x1));
    union { __half2 h; unsigned u; } cv; cv.h = hh;
    int pos = atomicAdd(&cursor[dst], 1);
    if (pos < CAP)
        ebuf[(long)dst * CAP + pos] = make_uint2(((unsigned)et << 17) | (unsigned)src, cv.u);
}

// ---------------- per-dst aggregation: wave per dst ----------------
__global__ __launch_bounds__(256) void agg_kernel(
        const int* __restrict__ cursor, const uint2* __restrict__ ebuf,
        const unsigned* __restrict__ h_b, const unsigned* __restrict__ rp_b,
        float* __restrict__ out_x) {
    int w = threadIdx.x >> 6, l = threadIdx.x & 63;
    int dst = blockIdx.x * 4 + w;           // grid = 25000, exact
    int cnt = cursor[dst];
    if (cnt > CAP) cnt = CAP;
    const uint2* base = ebuf + (long)dst * CAP;
    float acc0 = 0.f, acc1 = 0.f, den0 = 0.f, den1 = 0.f;
    int j = 0;
    for (; j + 3 < cnt; j += 4) {
        uint2 v0 = base[j], v1 = base[j + 1], v2 = base[j + 2], v3 = base[j + 3];
        union { __half2 h; unsigned u; } c0, c1, c2, c3;
        c0.u = v0.y; c1.u = v1.y; c2.u = v2.y; c3.u = v3.y;
        float2 e0 = __half22float2(c0.h), e1 = __half22float2(c1.h);
        float2 e2 = __half22float2(c2.h), e3 = __half22float2(c3.h);
        unsigned hb0 = h_b[(long)(v0.x & 0x1FFFF) * 64 + l];
        unsigned hb1 = h_b[(long)(v1.x & 0x1FFFF) * 64 + l];
        unsigned hb2 = h_b[(long)(v2.x & 0x1FFFF) * 64 + l];
        unsigned hb3 = h_b[(long)(v3.x & 0x1FFFF) * 64 + l];
        unsigned rb0 = rp_b[(v0.x >> 17) * 64 + l];
        unsigned rb1 = rp_b[(v1.x >> 17) * 64 + l];
        unsigned rb2 = rp_b[(v2.x >> 17) * 64 + l];
        unsigned rb3 = rp_b[(v3.x >> 17) * 64 + l];
        acc0 += e0.x * (blo(hb0) + blo(rb0)) + e1.x * (blo(hb1) + blo(rb1))
              + e2.x * (blo(hb2) + blo(rb2)) + e3.x * (blo(hb3) + blo(rb3));
        acc1 += e0.y * (bhi(hb0) + bhi(rb0)) + e1.y * (bhi(hb1) + bhi(rb1))
              + e2.y * (bhi(hb2) + bhi(rb2)) + e3.y * (bhi(hb3) + bhi(rb3));
        den0 += e0.x + e1.x + e2.x + e3.x;
        den1 += e0.y + e1.y + e2.y + e3.y;
    }
    for (; j < cnt; ++j) {
        uint2 v0 = base[j];
        union { __half2 h; unsigned u; } c0; c0.u = v0.y;
        float2 e0 = __half22float2(c0.h);
        unsigned hb = h_b[(long)(v0.x & 0x1FFFF) * 64 + l];
        unsigned rb = rp_b[(v0.x >> 17) * 64 + l];
        acc0 += e0.x * (blo(hb) + blo(rb));
        acc1 += e0.y * (bhi(hb) + bhi(rb));
        den0 += e0.x;
        den1 += e0.y;
    }
    float i0 = 1.0f / (den0 + 1e-16f), i1 = 1.0f / (den1 + 1e-16f);
    __builtin_nontemporal_store(tanhf(acc0 * i0), &out_x[(long)dst * GCN + l]);
    __builtin_nontemporal_store(tanhf(acc1 * i1), &out_x[(long)dst * GCN + 64 + l]);
}

// ---------------- sub gather ----------------
__global__ void gather_kernel(const int* __restrict__ sub, const float* __restrict__ out_x,
                              float* __restrict__ out_sub) {
    int idx = blockIdx.x * blockDim.x + threadIdx.x;
    if (idx >= B_SUB * GCN) return;
    int b = idx >> 7, d = idx & 127;
    out_sub[idx] = out_x[(long)sub[b] * GCN + d];
}

extern "C" void kernel_launch(void* const* d_in, const int* in_sizes, int n_in,
                              void* d_out, int out_size, void* d_ws, size_t ws_size,
                              hipStream_t stream) {
    const int* edge_index = (const int*)d_in[0];
    const int* edge_type  = (const int*)d_in[1];
    const int* ent_feature = (const int*)d_in[3];
    const int* sub = (const int*)d_in[4];
    const float* id_embed = (const float*)d_in[7];
    const float* gtab = (const float*)d_in[8];
    const float* atab = (const float*)d_in[9];
    const float* ltab = (const float*)d_in[10];
    const float* init_rel = (const float*)d_in[11];
    const float* W = (const float*)d_in[12];
    const float* Wr = (const float*)d_in[13];
    const float* att_src = (const float*)d_in[14];
    const float* att_dst = (const float*)d_in[15];
    const float* Wrel = (const float*)d_in[16];

    char* ws = (char*)d_ws;
    unsigned* h_b = (unsigned*)ws;                          ws += (long)N_NODES * 64 * 4;    // 25.6 MB
    unsigned* rp_b = (unsigned*)ws;                         ws += (long)NR2 * 64 * 4;
    float* rproj_att = (float*)ws;                          ws += NR2 * 2 * 4;
    float* hsrc_att = (float*)ws;                           ws += (long)N_NODES * 2 * 4;
    float* hdst_att = (float*)ws;                           ws += (long)N_NODES * 2 * 4;
    unsigned short* Wt = (unsigned short*)ws;               ws += (long)GCN * KPAD * 2;
    int* cursor = (int*)ws;                                 ws += (long)N_NODES * 4;
    uint2* ebuf = (uint2*)ws;                               ws += (long)N_NODES * CAP * 8;   // 51.2 MB

    float* out = (float*)d_out;
    float* out_sub = out;
    float* out_r = out + OUT_R_OFF;
    float* out_x = out + OUT_X_OFF;

    const int NB = (N_NODES + 255) / 256;   // 391

    wt_kernel<<<NB, 256, 0, stream>>>(W, Wt, cursor);       // also zeroes cursor
    rel_kernel<<<NR2, 256, 0, stream>>>(init_rel, Wr, Wrel, att_src, rp_b, rproj_att, out_r);
    hgemm_kernel<<<(N_NODES + 63) / 64, 256, 0, stream>>>(id_embed, gtab, atab, ltab,
                                                          ent_feature, Wt, att_src, att_dst,
                                                          h_b, hsrc_att, hdst_att);
    fill_kernel<<<(E_EDGES + 255) / 256, 256, 0, stream>>>(edge_index, edge_type, cursor,
                                                           (const float2*)hsrc_att,
                                                           (const float2*)rproj_att,
                                                           (const float2*)hdst_att, ebuf);
    agg_kernel<<<N_NODES / 4, 256, 0, stream>>>(cursor, ebuf, h_b, rp_b, out_x);
    gather_kernel<<<(B_SUB * GCN + 255) / 256, 256, 0, stream>>>(sub, out_x, out_sub);
}

// Round 5
// 229.702 us; speedup vs baseline: 1.1459x; 1.0173x over previous
//
#include <hip/hip_runtime.h>
#include <hip/hip_bf16.h>
#include <hip/hip_fp16.h>

#define N_NODES 100000
#define E_EDGES 400000
#define B_SUB 2048
#define INIT_DIM 100
#define UFD 100
#define ENT_DIM 400
#define GCN 128
#define NR2 100
#define KPAD 416           // 400 rounded up to 13*32
#define NCH 13             // K chunks of 32
#define CHK 32             // k per chunk
#define CAP 64             // bucket capacity per dst

typedef __attribute__((ext_vector_type(8))) short shortx8;
typedef __attribute__((ext_vector_type(4))) float floatx4;

#define OUT_R_OFF ((long)B_SUB * GCN)
#define OUT_X_OFF ((long)(B_SUB + NR2) * GCN)

__device__ __forceinline__ unsigned short f2b(float f) {
    unsigned u = __float_as_uint(f);
    u += 0x7fffu + ((u >> 16) & 1u);   // RNE to bf16
    return (unsigned short)(u >> 16);
}
__device__ __forceinline__ unsigned pk2(float x, float y) {
    return (unsigned)f2b(x) | ((unsigned)f2b(y) << 16);
}
// single-instruction packed RNE convert (bit-identical to pk2; harness-verified)
__device__ __forceinline__ unsigned cvtpk2(float x, float y) {
    unsigned r;
    asm("v_cvt_pk_bf16_f32 %0, %1, %2" : "=v"(r) : "v"(x), "v"(y));
    return r;
}
__device__ __forceinline__ float blo(unsigned u) { return __uint_as_float(u << 16); }
__device__ __forceinline__ float bhi(unsigned u) { return __uint_as_float(u & 0xFFFF0000u); }

// fast tanh: 1 - 2/(e^{2x}+1). Exact at +-inf; fp error ~1e-7 << bf16 noise.
__device__ __forceinline__ float fast_tanh(float x) {
    float e2 = __expf(2.f * x);
    return 1.f - 2.f / (e2 + 1.f);
}

// ---------------- W transpose + fp32->bf16 (also zeroes bucket cursors) ----------------
__global__ void wt_kernel(const float* __restrict__ W, unsigned short* __restrict__ Wt,
                          int* __restrict__ cursor) {
    int idx = blockIdx.x * 256 + threadIdx.x;
    if (idx < GCN * KPAD) {
        int n = idx & 127, k = idx >> 7;
        unsigned short o = 0;
        if (k < ENT_DIM) o = f2b(W[(long)k * GCN + n]);
        Wt[(long)n * KPAD + k] = o;
    }
    if (idx < N_NODES) cursor[idx] = 0;
}

// ---------------- relation GEMMs (tiny, fp32) ----------------
__global__ __launch_bounds__(256) void rel_kernel(
        const float* __restrict__ init_rel, const float* __restrict__ Wr,
        const float* __restrict__ Wrel, const float* __restrict__ att_src,
        unsigned* __restrict__ rp_b, float* __restrict__ rproj_att,
        float* __restrict__ out_r) {
    int rel = blockIdx.x;
    int t = threadIdx.x;            // 0..255
    int tx = t & 127, kh = t >> 7;  // output col, k-half
    __shared__ float rl[ENT_DIM];
    __shared__ float p1[2][128], p2[2][128];
    __shared__ float accbuf[128];
    for (int k = t; k < ENT_DIM; k += 256) rl[k] = init_rel[(long)rel * ENT_DIM + k];
    __syncthreads();
    float a1 = 0.f, a2 = 0.f;
    {
        const float* wr = Wr + (long)(kh * 200) * GCN + tx;
        const float* wl = Wrel + (long)(kh * 200) * GCN + tx;
        const float* rv = rl + kh * 200;
#pragma unroll 8
        for (int k = 0; k < 200; ++k) {
            float v = rv[k];
            a1 += v * wr[(long)k * GCN];
            a2 += v * wl[(long)k * GCN];
        }
    }
    p1[kh][tx] = a1;
    p2[kh][tx] = a2;
    __syncthreads();
    if (t < 128) {
        float acc1 = p1[0][tx] + p1[1][tx];
        float acc2 = p2[0][tx] + p2[1][tx];
        out_r[rel * GCN + tx] = acc2;
        accbuf[tx] = acc1;
        int head = tx >> 6, d = tx & 63;
        float v = acc1 * att_src[head * 64 + d];
        for (int off = 32; off > 0; off >>= 1) v += __shfl_down(v, off, 64);
        if (d == 0) rproj_att[rel * 2 + head] = v;
    }
    __syncthreads();
    if (t < 64) rp_b[rel * 64 + t] = pk2(accbuf[t], accbuf[t + 64]);
}

// ---------------- node GEMM h = init_embed @ W via bf16 MFMA ----------------
// (R4-verified: DMA staging + XOR swizzle + safe 2-phase sync. FROZEN.)
__global__ __launch_bounds__(256) void hgemm_kernel(
        const float* __restrict__ id_embed, const float* __restrict__ gtab,
        const float* __restrict__ atab, const float* __restrict__ ltab,
        const int* __restrict__ ent_feature, const unsigned short* __restrict__ Wt,
        const float* __restrict__ att_src, const float* __restrict__ att_dst,
        unsigned* __restrict__ h_b, float* __restrict__ hsrc_att, float* __restrict__ hdst_att) {
    __shared__ __align__(16) float As[2][64 * CHK];            // 8 KB per buf
    __shared__ __align__(16) unsigned short Bs[2][128 * CHK];  // 8 KB per buf

    int t = threadIdx.x;
    int w = t >> 6, lane = t & 63, quad = lane >> 4, l16 = lane & 15;
    int n0 = blockIdx.x * 64;

    int rA = t >> 3;
    int lA4 = ((t & 7) ^ (rA & 7)) * 4;        // logical k offset within chunk (floats)
    const float* segp[2][4];
#pragma unroll
    for (int rr = 0; rr < 2; ++rr) {
        int node = n0 + rr * 32 + rA;
        int nc = node < N_NODES ? node : N_NODES - 1;
        segp[rr][0] = id_embed + (long)nc * INIT_DIM;
        segp[rr][1] = gtab + ent_feature[nc * 3] * UFD;
        segp[rr][2] = atab + ent_feature[nc * 3 + 1] * UFD;
        segp[rr][3] = ltab + ent_feature[nc * 3 + 2] * UFD;
    }
    int cB = t >> 2;
    int lB8 = ((t & 3) ^ ((t >> 3) & 3)) * 8;  // shorts offset within chunk
    const unsigned short* bsrc0 = Wt + (long)cB * KPAD + lB8;
    const unsigned short* bsrc1 = Wt + (long)(64 + cB) * KPAD + lB8;

#define SEGPTR(rr_, kg_) ((kg_) < 100 ? segp[rr_][0] + (kg_) : \
                          (kg_) < 200 ? segp[rr_][1] + ((kg_) - 100) : \
                          (kg_) < 300 ? segp[rr_][2] + ((kg_) - 200) : \
                          (kg_) < 400 ? segp[rr_][3] + ((kg_) - 300) : segp[rr_][0])

#define STAGE(ch_, bi_) { \
    int kgA_ = (ch_) * CHK + lA4; \
    __builtin_amdgcn_global_load_lds( \
        (const __attribute__((address_space(1))) unsigned*)SEGPTR(0, kgA_), \
        (__attribute__((address_space(3))) unsigned*)((char*)&As[bi_][0] + w * 1024), 16, 0, 0); \
    __builtin_amdgcn_global_load_lds( \
        (const __attribute__((address_space(1))) unsigned*)SEGPTR(1, kgA_), \
        (__attribute__((address_space(3))) unsigned*)((char*)&As[bi_][0] + 4096 + w * 1024), 16, 0, 0); \
    __builtin_amdgcn_global_load_lds( \
        (const __attribute__((address_space(1))) unsigned*)(bsrc0 + (ch_) * CHK), \
        (__attribute__((address_space(3))) unsigned*)((char*)&Bs[bi_][0] + w * 1024), 16, 0, 0); \
    __builtin_amdgcn_global_load_lds( \
        (const __attribute__((address_space(1))) unsigned*)(bsrc1 + (ch_) * CHK), \
        (__attribute__((address_space(3))) unsigned*)((char*)&Bs[bi_][0] + 4096 + w * 1024), 16, 0, 0); \
}

    floatx4 acc[8];
#pragma unroll
    for (int c = 0; c < 8; ++c) acc[c] = (floatx4){0.f, 0.f, 0.f, 0.f};

    int xA0 = (2 * quad) ^ (l16 & 7);          // phys slot of logical granule 2q
    int xA1 = (2 * quad + 1) ^ (l16 & 7);      // phys slot of logical granule 2q+1
    int qB = quad ^ ((l16 >> 1) & 3);          // phys B slot

#define COMPUTE(bi_) { \
    const float* arow_ = &As[bi_][0] + (w * 16 + l16) * CHK; \
    float4 fa0_ = *(const float4*)(arow_ + xA0 * 4); \
    float4 fa1_ = *(const float4*)(arow_ + xA1 * 4); \
    uint4 u_; \
    u_.x = cvtpk2(fa0_.x, fa0_.y); u_.y = cvtpk2(fa0_.z, fa0_.w); \
    u_.z = cvtpk2(fa1_.x, fa1_.y); u_.w = cvtpk2(fa1_.z, fa1_.w); \
    shortx8 af_ = *(shortx8*)&u_; \
    _Pragma("unroll") for (int c = 0; c < 8; ++c) { \
        shortx8 b_ = *(const shortx8*)(&Bs[bi_][0] + (c * 16 + l16) * CHK + qB * 8); \
        acc[c] = __builtin_amdgcn_mfma_f32_16x16x32_bf16(af_, b_, acc[c], 0, 0, 0); \
    } \
}

    STAGE(0, 0);
#pragma unroll
    for (int ch = 0; ch < NCH; ++ch) {
        __syncthreads();                  // vmcnt(0)+barrier: buf[ch&1] landed everywhere
        if (ch + 1 < NCH) STAGE(ch + 1, (ch & 1) ^ 1);   // fire-and-forget under COMPUTE
        COMPUTE(ch & 1);
    }
#undef STAGE
#undef COMPUTE
#undef SEGPTR

    // epilogue: C/D layout col=lane&15 (-> c*16+l16), row=quad*4+reg (R0-verified)
    float attS_r[8], attD_r[8];
#pragma unroll
    for (int c = 0; c < 8; ++c) {
        attS_r[c] = att_src[c * 16 + l16];
        attD_r[c] = att_dst[c * 16 + l16];
    }
    int baseRow = n0 + w * 16 + quad * 4;
#pragma unroll
    for (int i = 0; i < 4; ++i) {
        int node = baseRow + i;
        bool ok = node < N_NODES;
#pragma unroll
        for (int c = 0; c < 4; ++c)
            if (ok) h_b[(long)node * 64 + c * 16 + l16] = cvtpk2(acc[c][i], acc[c + 4][i]);
        float s0 = 0.f, s1 = 0.f, d0 = 0.f, d1 = 0.f;
#pragma unroll
        for (int c = 0; c < 8; ++c) {
            float v = acc[c][i];
            if (c < 4) { s0 += v * attS_r[c]; d0 += v * attD_r[c]; }
            else       { s1 += v * attS_r[c]; d1 += v * attD_r[c]; }
        }
#pragma unroll
        for (int m = 1; m < 16; m <<= 1) {
            s0 += __shfl_xor(s0, m, 64);
            s1 += __shfl_xor(s1, m, 64);
            d0 += __shfl_xor(d0, m, 64);
            d1 += __shfl_xor(d1, m, 64);
        }
        if (ok && l16 == 0) {
            *(float2*)&hsrc_att[node * 2] = make_float2(s0, s1);
            *(float2*)&hdst_att[node * 2] = make_float2(d0, d1);
        }
    }
}

// ---------------- edge fill: bucket scatter, one 8B store per edge ----------------
__global__ void fill_kernel(const int* __restrict__ edge_index, const int* __restrict__ edge_type,
                            int* __restrict__ cursor,
                            const float2* __restrict__ hsrc2, const float2* __restrict__ rpa2,
                            const float2* __restrict__ hdst2,
                            uint2* __restrict__ ebuf) {
    int e = blockIdx.x * blockDim.x + threadIdx.x;
    if (e >= E_EDGES) return;
    int src = edge_index[e];
    int dst = edge_index[E_EDGES + e];
    int et = edge_type[e];
    float2 hs = hsrc2[src];
    float2 ra = rpa2[et];
    float2 hd = hdst2[dst];
    float x0 = hs.x + ra.x + hd.x;
    float x1 = hs.y + ra.y + hd.y;
    x0 = x0 > 0.f ? x0 : 0.2f * x0;      // leaky_relu(0.2)
    x1 = x1 > 0.f ? x1 : 0.2f * x1;
    __half2 hh = __floats2half2_rn(__expf(x0), __expf(x1));
    union { __half2 h; unsigned u; } cv; cv.h = hh;
    int pos = atomicAdd(&cursor[dst], 1);
    if (pos < CAP)
        ebuf[(long)dst * CAP + pos] = make_uint2(((unsigned)et << 17) | (unsigned)src, cv.u);
}

// ---------------- per-dst aggregation: wave per TWO dsts (interleaved, 2x MLP) ----------------
// v3: each wave serves dsts {2g, 2g+1}. The first uint4 entry-batches issue in
// parallel with the cursor loads (addresses are pure arithmetic; cnt only
// predicates). Predicated-off slots are bit-zeroed at the ENTRY so garbage
// can never decode to NaN (0-entry -> e=0, gathers hit valid h_b[l]/rp_b[l]).
__global__ __launch_bounds__(256) void agg_kernel(
        const int* __restrict__ cursor, const uint2* __restrict__ ebuf,
        const unsigned* __restrict__ h_b, const unsigned* __restrict__ rp_b,
        float* __restrict__ out_x) {
    int w = threadIdx.x >> 6, l = threadIdx.x & 63;
    int dstA = (blockIdx.x * 4 + w) * 2;      // grid = 12500 blocks, exact coverage
    int dstB = dstA + 1;
    const uint4* baseA = (const uint4*)(ebuf + (long)dstA * CAP);  // 2 entries / uint4
    const uint4* baseB = (const uint4*)(ebuf + (long)dstB * CAP);
    // batch 0 loads issue alongside cursor loads (no dependence)
    uint4 qA = baseA[0];
    uint4 qB = baseB[0];
    int cntA = cursor[dstA]; if (cntA > CAP) cntA = CAP;
    int cntB = cursor[dstB]; if (cntB > CAP) cntB = CAP;
    int jm = cntA > cntB ? cntA : cntB;

    float aA0 = 0.f, aA1 = 0.f, dA0 = 0.f, dA1 = 0.f;
    float aB0 = 0.f, aB1 = 0.f, dB0 = 0.f, dB1 = 0.f;

    for (int j = 0; j < jm; j += 2) {
        // bit-zero predicated-off entries
        unsigned iA0 = j     < cntA ? qA.x : 0u, eA0u = j     < cntA ? qA.y : 0u;
        unsigned iA1 = j + 1 < cntA ? qA.z : 0u, eA1u = j + 1 < cntA ? qA.w : 0u;
        unsigned iB0 = j     < cntB ? qB.x : 0u, eB0u = j     < cntB ? qB.y : 0u;
        unsigned iB1 = j + 1 < cntB ? qB.z : 0u, eB1u = j + 1 < cntB ? qB.w : 0u;
        // prefetch next batch (low pressure; loop-carried)
        if (j + 2 < jm) {
            qA = baseA[(j >> 1) + 1];
            qB = baseB[(j >> 1) + 1];
        }
        // 8 gathers in flight
        unsigned hbA0 = h_b[(long)(iA0 & 0x1FFFF) * 64 + l];
        unsigned hbA1 = h_b[(long)(iA1 & 0x1FFFF) * 64 + l];
        unsigned hbB0 = h_b[(long)(iB0 & 0x1FFFF) * 64 + l];
        unsigned hbB1 = h_b[(long)(iB1 & 0x1FFFF) * 64 + l];
        unsigned rbA0 = rp_b[(iA0 >> 17) * 64 + l];
        unsigned rbA1 = rp_b[(iA1 >> 17) * 64 + l];
        unsigned rbB0 = rp_b[(iB0 >> 17) * 64 + l];
        unsigned rbB1 = rp_b[(iB1 >> 17) * 64 + l];
        union { __half2 h; unsigned u; } cA0, cA1, cB0, cB1;
        cA0.u = eA0u; cA1.u = eA1u; cB0.u = eB0u; cB1.u = eB1u;
        float2 fA0 = __half22float2(cA0.h), fA1 = __half22float2(cA1.h);
        float2 fB0 = __half22float2(cB0.h), fB1 = __half22float2(cB1.h);
        aA0 += fA0.x * (blo(hbA0) + blo(rbA0)) + fA1.x * (blo(hbA1) + blo(rbA1));
        aA1 += fA0.y * (bhi(hbA0) + bhi(rbA0)) + fA1.y * (bhi(hbA1) + bhi(rbA1));
        aB0 += fB0.x * (blo(hbB0) + blo(rbB0)) + fB1.x * (blo(hbB1) + blo(rbB1));
        aB1 += fB0.y * (bhi(hbB0) + bhi(rbB0)) + fB1.y * (bhi(hbB1) + bhi(rbB1));
        dA0 += fA0.x + fA1.x;  dA1 += fA0.y + fA1.y;
        dB0 += fB0.x + fB1.x;  dB1 += fB0.y + fB1.y;
    }
    float rA0 = __builtin_amdgcn_rcpf(dA0 + 1e-16f);
    float rA1 = __builtin_amdgcn_rcpf(dA1 + 1e-16f);
    float rB0 = __builtin_amdgcn_rcpf(dB0 + 1e-16f);
    float rB1 = __builtin_amdgcn_rcpf(dB1 + 1e-16f);
    __builtin_nontemporal_store(fast_tanh(aA0 * rA0), &out_x[(long)dstA * GCN + l]);
    __builtin_nontemporal_store(fast_tanh(aA1 * rA1), &out_x[(long)dstA * GCN + 64 + l]);
    __builtin_nontemporal_store(fast_tanh(aB0 * rB0), &out_x[(long)dstB * GCN + l]);
    __builtin_nontemporal_store(fast_tanh(aB1 * rB1), &out_x[(long)dstB * GCN + 64 + l]);
}

// ---------------- sub gather ----------------
__global__ void gather_kernel(const int* __restrict__ sub, const float* __restrict__ out_x,
                              float* __restrict__ out_sub) {
    int idx = blockIdx.x * blockDim.x + threadIdx.x;
    if (idx >= B_SUB * GCN) return;
    int b = idx >> 7, d = idx & 127;
    out_sub[idx] = out_x[(long)sub[b] * GCN + d];
}

extern "C" void kernel_launch(void* const* d_in, const int* in_sizes, int n_in,
                              void* d_out, int out_size, void* d_ws, size_t ws_size,
                              hipStream_t stream) {
    const int* edge_index = (const int*)d_in[0];
    const int* edge_type  = (const int*)d_in[1];
    const int* ent_feature = (const int*)d_in[3];
    const int* sub = (const int*)d_in[4];
    const float* id_embed = (const float*)d_in[7];
    const float* gtab = (const float*)d_in[8];
    const float* atab = (const float*)d_in[9];
    const float* ltab = (const float*)d_in[10];
    const float* init_rel = (const float*)d_in[11];
    const float* W = (const float*)d_in[12];
    const float* Wr = (const float*)d_in[13];
    const float* att_src = (const float*)d_in[14];
    const float* att_dst = (const float*)d_in[15];
    const float* Wrel = (const float*)d_in[16];

    char* ws = (char*)d_ws;
    unsigned* h_b = (unsigned*)ws;                          ws += (long)N_NODES * 64 * 4;    // 25.6 MB
    unsigned* rp_b = (unsigned*)ws;                         ws += (long)NR2 * 64 * 4;
    float* rproj_att = (float*)ws;                          ws += NR2 * 2 * 4;
    float* hsrc_att = (float*)ws;                           ws += (long)N_NODES * 2 * 4;
    float* hdst_att = (float*)ws;                           ws += (long)N_NODES * 2 * 4;
    unsigned short* Wt = (unsigned short*)ws;               ws += (long)GCN * KPAD * 2;
    int* cursor = (int*)ws;                                 ws += (long)N_NODES * 4;
    uint2* ebuf = (uint2*)ws;                               ws += (long)N_NODES * CAP * 8;   // 51.2 MB

    float* out = (float*)d_out;
    float* out_sub = out;
    float* out_r = out + OUT_R_OFF;
    float* out_x = out + OUT_X_OFF;

    const int NB = (N_NODES + 255) / 256;   // 391

    wt_kernel<<<NB, 256, 0, stream>>>(W, Wt, cursor);       // also zeroes cursor
    rel_kernel<<<NR2, 256, 0, stream>>>(init_rel, Wr, Wrel, att_src, rp_b, rproj_att, out_r);
    hgemm_kernel<<<(N_NODES + 63) / 64, 256, 0, stream>>>(id_embed, gtab, atab, ltab,
                                                          ent_feature, Wt, att_src, att_dst,
                                                          h_b, hsrc_att, hdst_att);
    fill_kernel<<<(E_EDGES + 255) / 256, 256, 0, stream>>>(edge_index, edge_type, cursor,
                                                           (const float2*)hsrc_att,
                                                           (const float2*)rproj_att,
                                                           (const float2*)hdst_att, ebuf);
    agg_kernel<<<N_NODES / 8, 256, 0, stream>>>(cursor, ebuf, h_b, rp_b, out_x);
    gather_kernel<<<(B_SUB * GCN + 255) / 256, 256, 0, stream>>>(sub, out_x, out_sub);
}

// Round 6
// 228.762 us; speedup vs baseline: 1.1506x; 1.0041x over previous
//
#include <hip/hip_runtime.h>
#include <hip/hip_bf16.h>
#include <hip/hip_fp16.h>

#define N_NODES 100000
#define E_EDGES 400000
#define B_SUB 2048
#define INIT_DIM 100
#define UFD 100
#define ENT_DIM 400
#define GCN 128
#define NR2 100
#define KPAD 416           // 400 rounded up to 13*32
#define NCH 13             // K chunks of 32
#define CHK 32             // k per chunk
#define CAP 64             // bucket capacity per dst

typedef __attribute__((ext_vector_type(8))) short shortx8;
typedef __attribute__((ext_vector_type(4))) float floatx4;

#define OUT_R_OFF ((long)B_SUB * GCN)
#define OUT_X_OFF ((long)(B_SUB + NR2) * GCN)

__device__ __forceinline__ unsigned short f2b(float f) {
    unsigned u = __float_as_uint(f);
    u += 0x7fffu + ((u >> 16) & 1u);   // RNE to bf16
    return (unsigned short)(u >> 16);
}
__device__ __forceinline__ unsigned pk2(float x, float y) {
    return (unsigned)f2b(x) | ((unsigned)f2b(y) << 16);
}
// single-instruction packed RNE convert (bit-identical to pk2; harness-verified)
__device__ __forceinline__ unsigned cvtpk2(float x, float y) {
    unsigned r;
    asm("v_cvt_pk_bf16_f32 %0, %1, %2" : "=v"(r) : "v"(x), "v"(y));
    return r;
}
__device__ __forceinline__ float blo(unsigned u) { return __uint_as_float(u << 16); }
__device__ __forceinline__ float bhi(unsigned u) { return __uint_as_float(u & 0xFFFF0000u); }

// fast tanh: 1 - 2/(e^{2x}+1). Exact at +-inf; fp error ~1e-7 << bf16 noise.
__device__ __forceinline__ float fast_tanh(float x) {
    float e2 = __expf(2.f * x);
    return 1.f - 2.f / (e2 + 1.f);
}

// ---------------- W transpose + fp32->bf16 (also zeroes bucket cursors) ----------------
__global__ void wt_kernel(const float* __restrict__ W, unsigned short* __restrict__ Wt,
                          int* __restrict__ cursor) {
    int idx = blockIdx.x * 256 + threadIdx.x;
    if (idx < GCN * KPAD) {
        int n = idx & 127, k = idx >> 7;
        unsigned short o = 0;
        if (k < ENT_DIM) o = f2b(W[(long)k * GCN + n]);
        Wt[(long)n * KPAD + k] = o;
    }
    if (idx < N_NODES) cursor[idx] = 0;
}

// ---------------- relation GEMMs (tiny, fp32) ----------------
__global__ __launch_bounds__(256) void rel_kernel(
        const float* __restrict__ init_rel, const float* __restrict__ Wr,
        const float* __restrict__ Wrel, const float* __restrict__ att_src,
        unsigned* __restrict__ rp_b, float* __restrict__ rproj_att,
        float* __restrict__ out_r) {
    int rel = blockIdx.x;
    int t = threadIdx.x;            // 0..255
    int tx = t & 127, kh = t >> 7;  // output col, k-half
    __shared__ float rl[ENT_DIM];
    __shared__ float p1[2][128], p2[2][128];
    __shared__ float accbuf[128];
    for (int k = t; k < ENT_DIM; k += 256) rl[k] = init_rel[(long)rel * ENT_DIM + k];
    __syncthreads();
    float a1 = 0.f, a2 = 0.f;
    {
        const float* wr = Wr + (long)(kh * 200) * GCN + tx;
        const float* wl = Wrel + (long)(kh * 200) * GCN + tx;
        const float* rv = rl + kh * 200;
#pragma unroll 8
        for (int k = 0; k < 200; ++k) {
            float v = rv[k];
            a1 += v * wr[(long)k * GCN];
            a2 += v * wl[(long)k * GCN];
        }
    }
    p1[kh][tx] = a1;
    p2[kh][tx] = a2;
    __syncthreads();
    if (t < 128) {
        float acc1 = p1[0][tx] + p1[1][tx];
        float acc2 = p2[0][tx] + p2[1][tx];
        out_r[rel * GCN + tx] = acc2;
        accbuf[tx] = acc1;
        int head = tx >> 6, d = tx & 63;
        float v = acc1 * att_src[head * 64 + d];
        for (int off = 32; off > 0; off >>= 1) v += __shfl_down(v, off, 64);
        if (d == 0) rproj_att[rel * 2 + head] = v;
    }
    __syncthreads();
    if (t < 64) rp_b[rel * 64 + t] = pk2(accbuf[t], accbuf[t + 64]);
}

// ---------------- node GEMM h = init_embed @ W via bf16 MFMA ----------------
// v6: B-only LDS staging (16 KB, XOR swizzle, DMA + safe 2-phase sync as
// verified in R4). A loaded straight to registers per-lane (R2-verified
// path: lane's fragment = its own row's 8 contiguous k-floats), with a
// 1-chunk prefetch issued BEFORE the barrier: since __syncthreads drains
// vmcnt(0) anyway, A latency merges into the same stall as the B-DMA
// drain, and the fence makes the prefetch un-sinkable by the compiler.
// 16 KB LDS + VGPR cap 85 -> 6 blocks/CU (24 waves/CU TLP).
__global__ __launch_bounds__(256, 6) void hgemm_kernel(
        const float* __restrict__ id_embed, const float* __restrict__ gtab,
        const float* __restrict__ atab, const float* __restrict__ ltab,
        const int* __restrict__ ent_feature, const unsigned short* __restrict__ Wt,
        const float* __restrict__ att_src, const float* __restrict__ att_dst,
        unsigned* __restrict__ h_b, float* __restrict__ hsrc_att, float* __restrict__ hdst_att) {
    __shared__ __align__(16) unsigned short Bs[2][128 * CHK];  // 8 KB per buf

    int t = threadIdx.x;
    int w = t >> 6, lane = t & 63, quad = lane >> 4, l16 = lane & 15;
    int n0 = blockIdx.x * 64;

    // ---- A: per-lane row pointers (this lane's MFMA A-frag rows) ----
    int nrow = n0 + w * 16 + l16;
    int nc = nrow < N_NODES ? nrow : N_NODES - 1;
    const float* pid = id_embed + (long)nc * INIT_DIM;
    const float* pg  = gtab + ent_feature[nc * 3] * UFD;
    const float* pa  = atab + ent_feature[nc * 3 + 1] * UFD;
    const float* pl  = ltab + ent_feature[nc * 3 + 2] * UFD;

    // ---- B staging: thread t feeds cols {t>>2, 64+(t>>2)}, phys slot t&3;
    //      supplies logical slot (t&3) ^ ((col>>1)&3) = (t&3) ^ ((t>>3)&3).
    int cB = t >> 2;
    int lB8 = ((t & 3) ^ ((t >> 3) & 3)) * 8;  // shorts offset within chunk
    const unsigned short* bsrc0 = Wt + (long)cB * KPAD + lB8;
    const unsigned short* bsrc1 = Wt + (long)(64 + cB) * KPAD + lB8;

#define SEGPTR(kg_) ((kg_) < 100 ? pid + (kg_) : \
                     (kg_) < 200 ? pg + ((kg_) - 100) : \
                     (kg_) < 300 ? pa + ((kg_) - 200) : \
                     (kg_) < 400 ? pl + ((kg_) - 300) : pid)  // k>=400: zero Wt rows

#define STAGE(ch_, bi_) { \
    __builtin_amdgcn_global_load_lds( \
        (const __attribute__((address_space(1))) unsigned*)(bsrc0 + (ch_) * CHK), \
        (__attribute__((address_space(3))) unsigned*)((char*)&Bs[bi_][0] + w * 1024), 16, 0, 0); \
    __builtin_amdgcn_global_load_lds( \
        (const __attribute__((address_space(1))) unsigned*)(bsrc1 + (ch_) * CHK), \
        (__attribute__((address_space(3))) unsigned*)((char*)&Bs[bi_][0] + 4096 + w * 1024), 16, 0, 0); \
}

    floatx4 acc[8];
#pragma unroll
    for (int c = 0; c < 8; ++c) acc[c] = (floatx4){0.f, 0.f, 0.f, 0.f};

    int qB = quad ^ ((l16 >> 1) & 3);          // B read-side phys slot (swizzle)

    // prologue: B chunk 0 DMA + A chunk 0 register prefetch
    STAGE(0, 0);
    float4 va = *(const float4*)SEGPTR(quad * 8);
    float4 vb = *(const float4*)SEGPTR(quad * 8 + 4);

#pragma unroll
    for (int ch = 0; ch < NCH; ++ch) {
        __syncthreads();   // vmcnt(0)+barrier: B(ch) landed everywhere; A(ch) in regs
        if (ch + 1 < NCH) STAGE(ch + 1, (ch & 1) ^ 1);   // fire-and-forget under compute
        uint4 u_;
        u_.x = cvtpk2(va.x, va.y); u_.y = cvtpk2(va.z, va.w);
        u_.z = cvtpk2(vb.x, vb.y); u_.w = cvtpk2(vb.z, vb.w);
        shortx8 af_ = *(shortx8*)&u_;
        if (ch + 1 < NCH) {                      // A(ch+1) prefetch: flies under MFMAs,
            int kg = (ch + 1) * CHK + quad * 8;  // drained by next barrier (un-sinkable)
            va = *(const float4*)SEGPTR(kg);
            vb = *(const float4*)SEGPTR(kg + 4);
        }
#pragma unroll
        for (int c = 0; c < 8; ++c) {
            shortx8 b_ = *(const shortx8*)(&Bs[ch & 1][0] + (c * 16 + l16) * CHK + qB * 8);
            acc[c] = __builtin_amdgcn_mfma_f32_16x16x32_bf16(af_, b_, acc[c], 0, 0, 0);
        }
    }
#undef STAGE
#undef SEGPTR

    // epilogue: C/D layout col=lane&15 (-> c*16+l16), row=quad*4+reg (R0-verified)
    float attS_r[8], attD_r[8];
#pragma unroll
    for (int c = 0; c < 8; ++c) {
        attS_r[c] = att_src[c * 16 + l16];
        attD_r[c] = att_dst[c * 16 + l16];
    }
    int baseRow = n0 + w * 16 + quad * 4;
#pragma unroll
    for (int i = 0; i < 4; ++i) {
        int node = baseRow + i;
        bool ok = node < N_NODES;
#pragma unroll
        for (int c = 0; c < 4; ++c)
            if (ok) h_b[(long)node * 64 + c * 16 + l16] = cvtpk2(acc[c][i], acc[c + 4][i]);
        float s0 = 0.f, s1 = 0.f, d0 = 0.f, d1 = 0.f;
#pragma unroll
        for (int c = 0; c < 8; ++c) {
            float v = acc[c][i];
            if (c < 4) { s0 += v * attS_r[c]; d0 += v * attD_r[c]; }
            else       { s1 += v * attS_r[c]; d1 += v * attD_r[c]; }
        }
#pragma unroll
        for (int m = 1; m < 16; m <<= 1) {
            s0 += __shfl_xor(s0, m, 64);
            s1 += __shfl_xor(s1, m, 64);
            d0 += __shfl_xor(d0, m, 64);
            d1 += __shfl_xor(d1, m, 64);
        }
        if (ok && l16 == 0) {
            *(float2*)&hsrc_att[node * 2] = make_float2(s0, s1);
            *(float2*)&hdst_att[node * 2] = make_float2(d0, d1);
        }
    }
}

// ---------------- edge fill: bucket scatter, one 8B store per edge ----------------
__global__ void fill_kernel(const int* __restrict__ edge_index, const int* __restrict__ edge_type,
                            int* __restrict__ cursor,
                            const float2* __restrict__ hsrc2, const float2* __restrict__ rpa2,
                            const float2* __restrict__ hdst2,
                            uint2* __restrict__ ebuf) {
    int e = blockIdx.x * blockDim.x + threadIdx.x;
    if (e >= E_EDGES) return;
    int src = edge_index[e];
    int dst = edge_index[E_EDGES + e];
    int et = edge_type[e];
    float2 hs = hsrc2[src];
    float2 ra = rpa2[et];
    float2 hd = hdst2[dst];
    float x0 = hs.x + ra.x + hd.x;
    float x1 = hs.y + ra.y + hd.y;
    x0 = x0 > 0.f ? x0 : 0.2f * x0;      // leaky_relu(0.2)
    x1 = x1 > 0.f ? x1 : 0.2f * x1;
    __half2 hh = __floats2half2_rn(__expf(x0), __expf(x1));
    union { __half2 h; unsigned u; } cv; cv.h = hh;
    int pos = atomicAdd(&cursor[dst], 1);
    if (pos < CAP)
        ebuf[(long)dst * CAP + pos] = make_uint2(((unsigned)et << 17) | (unsigned)src, cv.u);
}

// ---------------- per-dst aggregation: wave per TWO dsts (interleaved, 2x MLP) ----------------
__global__ __launch_bounds__(256) void agg_kernel(
        const int* __restrict__ cursor, const uint2* __restrict__ ebuf,
        const unsigned* __restrict__ h_b, const unsigned* __restrict__ rp_b,
        float* __restrict__ out_x) {
    int w = threadIdx.x >> 6, l = threadIdx.x & 63;
    int dstA = (blockIdx.x * 4 + w) * 2;      // grid = 12500 blocks, exact coverage
    int dstB = dstA + 1;
    const uint4* baseA = (const uint4*)(ebuf + (long)dstA * CAP);  // 2 entries / uint4
    const uint4* baseB = (const uint4*)(ebuf + (long)dstB * CAP);
    // batch 0 loads issue alongside cursor loads (no dependence)
    uint4 qA = baseA[0];
    uint4 qB = baseB[0];
    int cntA = cursor[dstA]; if (cntA > CAP) cntA = CAP;
    int cntB = cursor[dstB]; if (cntB > CAP) cntB = CAP;
    int jm = cntA > cntB ? cntA : cntB;

    float aA0 = 0.f, aA1 = 0.f, dA0 = 0.f, dA1 = 0.f;
    float aB0 = 0.f, aB1 = 0.f, dB0 = 0.f, dB1 = 0.f;

    for (int j = 0; j < jm; j += 2) {
        // bit-zero predicated-off entries
        unsigned iA0 = j     < cntA ? qA.x : 0u, eA0u = j     < cntA ? qA.y : 0u;
        unsigned iA1 = j + 1 < cntA ? qA.z : 0u, eA1u = j + 1 < cntA ? qA.w : 0u;
        unsigned iB0 = j     < cntB ? qB.x : 0u, eB0u = j     < cntB ? qB.y : 0u;
        unsigned iB1 = j + 1 < cntB ? qB.z : 0u, eB1u = j + 1 < cntB ? qB.w : 0u;
        // prefetch next batch (low pressure; loop-carried)
        if (j + 2 < jm) {
            qA = baseA[(j >> 1) + 1];
            qB = baseB[(j >> 1) + 1];
        }
        // 8 gathers in flight
        unsigned hbA0 = h_b[(long)(iA0 & 0x1FFFF) * 64 + l];
        unsigned hbA1 = h_b[(long)(iA1 & 0x1FFFF) * 64 + l];
        unsigned hbB0 = h_b[(long)(iB0 & 0x1FFFF) * 64 + l];
        unsigned hbB1 = h_b[(long)(iB1 & 0x1FFFF) * 64 + l];
        unsigned rbA0 = rp_b[(iA0 >> 17) * 64 + l];
        unsigned rbA1 = rp_b[(iA1 >> 17) * 64 + l];
        unsigned rbB0 = rp_b[(iB0 >> 17) * 64 + l];
        unsigned rbB1 = rp_b[(iB1 >> 17) * 64 + l];
        union { __half2 h; unsigned u; } cA0, cA1, cB0, cB1;
        cA0.u = eA0u; cA1.u = eA1u; cB0.u = eB0u; cB1.u = eB1u;
        float2 fA0 = __half22float2(cA0.h), fA1 = __half22float2(cA1.h);
        float2 fB0 = __half22float2(cB0.h), fB1 = __half22float2(cB1.h);
        aA0 += fA0.x * (blo(hbA0) + blo(rbA0)) + fA1.x * (blo(hbA1) + blo(rbA1));
        aA1 += fA0.y * (bhi(hbA0) + bhi(rbA0)) + fA1.y * (bhi(hbA1) + bhi(rbA1));
        aB0 += fB0.x * (blo(hbB0) + blo(rbB0)) + fB1.x * (blo(hbB1) + blo(rbB1));
        aB1 += fB0.y * (bhi(hbB0) + bhi(rbB0)) + fB1.y * (bhi(hbB1) + bhi(rbB1));
        dA0 += fA0.x + fA1.x;  dA1 += fA0.y + fA1.y;
        dB0 += fB0.x + fB1.x;  dB1 += fB0.y + fB1.y;
    }
    float rA0 = __builtin_amdgcn_rcpf(dA0 + 1e-16f);
    float rA1 = __builtin_amdgcn_rcpf(dA1 + 1e-16f);
    float rB0 = __builtin_amdgcn_rcpf(dB0 + 1e-16f);
    float rB1 = __builtin_amdgcn_rcpf(dB1 + 1e-16f);
    __builtin_nontemporal_store(fast_tanh(aA0 * rA0), &out_x[(long)dstA * GCN + l]);
    __builtin_nontemporal_store(fast_tanh(aA1 * rA1), &out_x[(long)dstA * GCN + 64 + l]);
    __builtin_nontemporal_store(fast_tanh(aB0 * rB0), &out_x[(long)dstB * GCN + l]);
    __builtin_nontemporal_store(fast_tanh(aB1 * rB1), &out_x[(long)dstB * GCN + 64 + l]);
}

// ---------------- sub gather ----------------
__global__ void gather_kernel(const int* __restrict__ sub, const float* __restrict__ out_x,
                              float* __restrict__ out_sub) {
    int idx = blockIdx.x * blockDim.x + threadIdx.x;
    if (idx >= B_SUB * GCN) return;
    int b = idx >> 7, d = idx & 127;
    out_sub[idx] = out_x[(long)sub[b] * GCN + d];
}

extern "C" void kernel_launch(void* const* d_in, const int* in_sizes, int n_in,
                              void* d_out, int out_size, void* d_ws, size_t ws_size,
                              hipStream_t stream) {
    const int* edge_index = (const int*)d_in[0];
    const int* edge_type  = (const int*)d_in[1];
    const int* ent_feature = (const int*)d_in[3];
    const int* sub = (const int*)d_in[4];
    const float* id_embed = (const float*)d_in[7];
    const float* gtab = (const float*)d_in[8];
    const float* atab = (const float*)d_in[9];
    const float* ltab = (const float*)d_in[10];
    const float* init_rel = (const float*)d_in[11];
    const float* W = (const float*)d_in[12];
    const float* Wr = (const float*)d_in[13];
    const float* att_src = (const float*)d_in[14];
    const float* att_dst = (const float*)d_in[15];
    const float* Wrel = (const float*)d_in[16];

    char* ws = (char*)d_ws;
    unsigned* h_b = (unsigned*)ws;                          ws += (long)N_NODES * 64 * 4;    // 25.6 MB
    unsigned* rp_b = (unsigned*)ws;                         ws += (long)NR2 * 64 * 4;
    float* rproj_att = (float*)ws;                          ws += NR2 * 2 * 4;
    float* hsrc_att = (float*)ws;                           ws += (long)N_NODES * 2 * 4;
    float* hdst_att = (float*)ws;                           ws += (long)N_NODES * 2 * 4;
    unsigned short* Wt = (unsigned short*)ws;               ws += (long)GCN * KPAD * 2;
    int* cursor = (int*)ws;                                 ws += (long)N_NODES * 4;
    uint2* ebuf = (uint2*)ws;                               ws += (long)N_NODES * CAP * 8;   // 51.2 MB

    float* out = (float*)d_out;
    float* out_sub = out;
    float* out_r = out + OUT_R_OFF;
    float* out_x = out + OUT_X_OFF;

    const int NB = (N_NODES + 255) / 256;   // 391

    wt_kernel<<<NB, 256, 0, stream>>>(W, Wt, cursor);       // also zeroes cursor
    rel_kernel<<<NR2, 256, 0, stream>>>(init_rel, Wr, Wrel, att_src, rp_b, rproj_att, out_r);
    hgemm_kernel<<<(N_NODES + 63) / 64, 256, 0, stream>>>(id_embed, gtab, atab, ltab,
                                                          ent_feature, Wt, att_src, att_dst,
                                                          h_b, hsrc_att, hdst_att);
    fill_kernel<<<(E_EDGES + 255) / 256, 256, 0, stream>>>(edge_index, edge_type, cursor,
                                                           (const float2*)hsrc_att,
                                                           (const float2*)rproj_att,
                                                           (const float2*)hdst_att, ebuf);
    agg_kernel<<<N_NODES / 8, 256, 0, stream>>>(cursor, ebuf, h_b, rp_b, out_x);
    gather_kernel<<<(B_SUB * GCN + 255) / 256, 256, 0, stream>>>(sub, out_x, out_sub);
}